// Round 1
// baseline (186.897 us; speedup 1.0000x reference)
//
#include <hip/hip_runtime.h>

typedef unsigned short u16;
typedef unsigned int u32;
typedef unsigned long long u64;

typedef __attribute__((ext_vector_type(8))) short short8;
typedef __attribute__((ext_vector_type(4))) float f32x4;

#define DEVI static __device__ __forceinline__

DEVI u16 f2bf(float f) {
  u32 u = __float_as_uint(f);
  return (u16)((u + 0x7fffu + ((u >> 16) & 1u)) >> 16);
}

DEVI u64 pack4f(float a, float b, float c, float d) {
  return (u64)f2bf(a) | ((u64)f2bf(b) << 16) | ((u64)f2bf(c) << 32) |
         ((u64)f2bf(d) << 48);
}

DEVI void gld_lds16(const void* g, void* l) {
  __builtin_amdgcn_global_load_lds(
      (const __attribute__((address_space(1))) void*)g,
      (__attribute__((address_space(3))) void*)l, 16, 0, 0);
}

DEVI f32x4 mfma16(short8 a, short8 b, f32x4 c) {
  return __builtin_amdgcn_mfma_f32_16x16x32_bf16(a, b, c, 0, 0, 0);
}

DEVI f32x4 zero4() {
  f32x4 z = {0.f, 0.f, 0.f, 0.f};
  return z;
}

// ---------------------------------------------------------------- fp32->bf16
__global__ __launch_bounds__(256) void cvt_bf16(const float* __restrict__ s,
                                                u16* __restrict__ d, int n4) {
  int i = blockIdx.x * 256 + threadIdx.x;
  int stride = gridDim.x * 256;
  for (; i < n4; i += stride) {
    f32x4 v = ((const f32x4*)s)[i];
    ((u64*)d)[i] = pack4f(v.x, v.y, v.z, v.w);
  }
}

// ------------------------------------------------- GEMM1: qkv = W_qkv @ x^T
// C'[f, m] = sum_c W[f,c] * X[m,c].  A=W [3072,1024], B=X [8192,1024].
// Epilogue: f<2048 -> Q/K as [B,H,N,D] bf16 (LDS transpose, coalesced);
//           f>=2048 -> V^T as [B,H,D,N] bf16 (direct scalar stores).
__global__ __launch_bounds__(256, 2) void gemm_qkv(
    const u16* __restrict__ W, const u16* __restrict__ X, u16* __restrict__ Q,
    u16* __restrict__ K, u16* __restrict__ V) {
  __shared__ alignas(16) char smem[36864];
  u16* As = (u16*)smem;
  u16* Bs = (u16*)(smem + 8192);

  const int tid = threadIdx.x;
  const int wid = tid >> 6, lane = tid & 63;
  const int lr = lane & 15, lg = lane >> 4;
  const int wr = wid >> 1, wc = wid & 1;
  const int f_base = blockIdx.y * 128;
  const int m_base = blockIdx.x * 128;

  f32x4 acc[4][4];
#pragma unroll
  for (int i = 0; i < 4; ++i)
#pragma unroll
    for (int j = 0; j < 4; ++j) acc[i][j] = zero4();

  const int srow = tid >> 2;
  const int scol = (tid & 3) << 4;  // bytes within 64B row-chunk
  const char* Ag = (const char*)(W + (u64)f_base * 1024) + (u64)srow * 2048 + scol;
  const char* Bg = (const char*)(X + (u64)m_base * 1024) + (u64)srow * 2048 + scol;
  char* Asd = (char*)As + tid * 16;
  char* Bsd = (char*)Bs + tid * 16;

  for (int kt = 0; kt < 32; ++kt) {
    const int kb = kt * 64;  // bytes into K
    gld_lds16(Ag + kb, Asd);
    gld_lds16(Ag + kb + 64 * 2048, Asd + 4096);
    gld_lds16(Bg + kb, Bsd);
    gld_lds16(Bg + kb + 64 * 2048, Bsd + 4096);
    __syncthreads();
    short8 af[4], bf[4];
#pragma unroll
    for (int mi = 0; mi < 4; ++mi)
      af[mi] = *(const short8*)(As + (wr * 64 + mi * 16 + lr) * 32 + lg * 8);
#pragma unroll
    for (int ni = 0; ni < 4; ++ni)
      bf[ni] = *(const short8*)(Bs + (wc * 64 + ni * 16 + lr) * 32 + lg * 8);
#pragma unroll
    for (int mi = 0; mi < 4; ++mi)
#pragma unroll
      for (int ni = 0; ni < 4; ++ni)
        acc[mi][ni] = mfma16(af[mi], bf[ni], acc[mi][ni]);
    __syncthreads();
  }

  const int f0 = f_base + wr * 64;
  const int m0 = m_base + wc * 64;
  const int b = m0 >> 10, n0 = m0 & 1023;
  const int which = f0 >> 10;        // 0=Q 1=K 2=V, uniform per block
  const int h = (f0 & 1023) >> 6;
  const int bh = b * 16 + h;

  if (which < 2) {
    u16* Ob = (u16*)smem + wid * (64 * 72);
#pragma unroll
    for (int mi = 0; mi < 4; ++mi)
#pragma unroll
      for (int ni = 0; ni < 4; ++ni) {
        int ml = ni * 16 + lr;
        int fl = mi * 16 + lg * 4;
        *(u64*)(Ob + ml * 72 + fl) =
            pack4f(acc[mi][ni].x, acc[mi][ni].y, acc[mi][ni].z, acc[mi][ni].w);
      }
    __syncthreads();
    u16* dst = (which ? K : Q) + ((u64)bh * 1024 + n0) * 64;
#pragma unroll
    for (int it = 0; it < 8; ++it) {
      int ml = it * 8 + (lane >> 3);
      int c = lane & 7;
      *(short8*)(dst + ml * 64 + c * 8) = *(const short8*)(Ob + ml * 72 + c * 8);
    }
  } else {
    u16* dst = V + (u64)bh * 64 * 1024;
#pragma unroll
    for (int mi = 0; mi < 4; ++mi) {
      int d0 = mi * 16 + lg * 4;
#pragma unroll
      for (int ni = 0; ni < 4; ++ni) {
        int n = n0 + ni * 16 + lr;
#pragma unroll
        for (int r = 0; r < 4; ++r)
          dst[(u64)(d0 + r) * 1024 + n] = f2bf(acc[mi][ni][r]);
      }
    }
  }
}

// ------------------------------------------------------------ flash attention
// Per block: one (b,h), 64 q rows (4 waves x 16).  KV tile = 64.
// S^T = K*Q^T (swapped) so each lane owns one q's scores; online softmax;
// P repacked via per-wave LDS; O^T = V^T * P^T.
__global__ __launch_bounds__(256, 2) void attn_fwd(const u16* __restrict__ Q,
                                                   const u16* __restrict__ K,
                                                   const u16* __restrict__ V,
                                                   u16* __restrict__ AO) {
  __shared__ alignas(16) u16 Ks[64 * 64];
  __shared__ alignas(16) u16 Vs[64 * 64];
  __shared__ alignas(16) u16 Pb[4 * 16 * 72];

  const int tid = threadIdx.x;
  const int wid = tid >> 6, lane = tid & 63;
  const int lr = lane & 15, lg = lane >> 4;
  const int bh = blockIdx.x >> 4, qblk = blockIdx.x & 15;

  const u64 kvbase = (u64)bh * (1024 * 64);
  const int q0 = qblk * 64 + wid * 16;

  const u16* qp = Q + kvbase + (u64)(q0 + lr) * 64 + lg * 8;
  const short8 qf0 = *(const short8*)qp;
  const short8 qf1 = *(const short8*)(qp + 32);

  float m_run = -INFINITY, l_run = 0.f;
  f32x4 oacc[4];
#pragma unroll
  for (int i = 0; i < 4; ++i) oacc[i] = zero4();

  const float SC = 0.125f * 1.44269504088896f;  // scale * log2(e)

  u16* Pw = Pb + wid * (16 * 72);
  const int t2 = tid + 256;
  const int r1 = tid >> 3, c1 = tid & 7;
  const int r2 = t2 >> 3, c2 = t2 & 7;

  const char* kgb = (const char*)(K + kvbase);
  const char* vgb = (const char*)(V + kvbase);

  for (int kt = 0; kt < 16; ++kt) {
    // stage K tile (contiguous 8KB) and V^T tile, XOR-swizzled global source
    const char* kg = kgb + kt * 8192;
    gld_lds16(kg + r1 * 128 + ((c1 ^ (r1 & 7)) << 4), (char*)Ks + tid * 16);
    gld_lds16(kg + r2 * 128 + ((c2 ^ (r2 & 7)) << 4), (char*)Ks + t2 * 16);
    const char* vg = vgb + kt * 128;
    gld_lds16(vg + r1 * 2048 + ((c1 ^ (r1 & 7)) << 4), (char*)Vs + tid * 16);
    gld_lds16(vg + r2 * 2048 + ((c2 ^ (r2 & 7)) << 4), (char*)Vs + t2 * 16);
    __syncthreads();

    // S^T = K * Q^T
    f32x4 sacc[4];
#pragma unroll
    for (int m4 = 0; m4 < 4; ++m4) sacc[m4] = zero4();
#pragma unroll
    for (int m4 = 0; m4 < 4; ++m4) {
      int key = m4 * 16 + lr;
      int sw = key & 7;
      short8 kf0 = *(const short8*)(Ks + key * 64 + ((lg ^ sw) << 3));
      short8 kf1 = *(const short8*)(Ks + key * 64 + (((lg + 4) ^ sw) << 3));
      sacc[m4] = mfma16(kf0, qf0, sacc[m4]);
      sacc[m4] = mfma16(kf1, qf1, sacc[m4]);
    }

    // online softmax (each q owned by 4 lanes: lr, +16, +32, +48)
    float pmax = -INFINITY;
#pragma unroll
    for (int m4 = 0; m4 < 4; ++m4)
#pragma unroll
      for (int r = 0; r < 4; ++r) pmax = fmaxf(pmax, sacc[m4][r]);
    pmax = fmaxf(pmax, __shfl_xor(pmax, 16));
    pmax = fmaxf(pmax, __shfl_xor(pmax, 32));
    float m_new = fmaxf(m_run, pmax);
    float alpha = exp2f((m_run - m_new) * SC);
    float psum = 0.f;
    float p[16];
#pragma unroll
    for (int m4 = 0; m4 < 4; ++m4)
#pragma unroll
      for (int r = 0; r < 4; ++r) {
        float e = exp2f((sacc[m4][r] - m_new) * SC);
        p[m4 * 4 + r] = e;
        psum += e;
      }
    psum += __shfl_xor(psum, 16);
    psum += __shfl_xor(psum, 32);
    l_run = l_run * alpha + psum;
    m_run = m_new;
#pragma unroll
    for (int dt = 0; dt < 4; ++dt) oacc[dt] *= alpha;

    // repack P (bf16) into per-wave LDS: Pw[q][key]
#pragma unroll
    for (int m4 = 0; m4 < 4; ++m4)
      *(u64*)(Pw + lr * 72 + m4 * 16 + lg * 4) =
          pack4f(p[m4 * 4], p[m4 * 4 + 1], p[m4 * 4 + 2], p[m4 * 4 + 3]);
    __syncthreads();

    short8 pf0 = *(const short8*)(Pw + lr * 72 + lg * 8);
    short8 pf1 = *(const short8*)(Pw + lr * 72 + 32 + lg * 8);
#pragma unroll
    for (int dt = 0; dt < 4; ++dt) {
      int d = dt * 16 + lr;
      int sw = d & 7;
      short8 vf0 = *(const short8*)(Vs + d * 64 + ((lg ^ sw) << 3));
      short8 vf1 = *(const short8*)(Vs + d * 64 + (((lg + 4) ^ sw) << 3));
      oacc[dt] = mfma16(vf0, pf0, oacc[dt]);
      oacc[dt] = mfma16(vf1, pf1, oacc[dt]);
    }
    __syncthreads();
  }

  // epilogue: normalize, transpose via LDS, coalesced store to [B,N,C]
  float inv_l = 1.f / l_run;
#pragma unroll
  for (int dt = 0; dt < 4; ++dt) {
    f32x4 o = oacc[dt] * inv_l;
    *(u64*)(Pw + lr * 72 + dt * 16 + lg * 4) = pack4f(o.x, o.y, o.z, o.w);
  }
  __syncthreads();
  const int b = bh >> 4, h = bh & 15;
  u16* dst = AO + ((u64)(b * 1024 + q0) * 1024) + h * 64;
#pragma unroll
  for (int it = 0; it < 2; ++it) {
    int ql = it * 8 + (lane >> 3);
    int c = lane & 7;
    *(short8*)(dst + (u64)ql * 1024 + c * 8) = *(const short8*)(Pw + ql * 72 + c * 8);
  }
}

// ----------------------------------------------- GEMM2: out = AO @ Wp^T + b
// C'[f, m] orientation; fp32 output with fused bias, f32x4 stores.
__global__ __launch_bounds__(256, 2) void gemm_proj(const u16* __restrict__ W,
                                                    const u16* __restrict__ X,
                                                    const float* __restrict__ bias,
                                                    float* __restrict__ Out) {
  __shared__ alignas(16) char smem[16384];
  u16* As = (u16*)smem;
  u16* Bs = (u16*)(smem + 8192);

  const int tid = threadIdx.x;
  const int wid = tid >> 6, lane = tid & 63;
  const int lr = lane & 15, lg = lane >> 4;
  const int wr = wid >> 1, wc = wid & 1;
  const int f_base = blockIdx.y * 128;
  const int m_base = blockIdx.x * 128;

  f32x4 acc[4][4];
#pragma unroll
  for (int i = 0; i < 4; ++i)
#pragma unroll
    for (int j = 0; j < 4; ++j) acc[i][j] = zero4();

  const int srow = tid >> 2;
  const int scol = (tid & 3) << 4;
  const char* Ag = (const char*)(W + (u64)f_base * 1024) + (u64)srow * 2048 + scol;
  const char* Bg = (const char*)(X + (u64)m_base * 1024) + (u64)srow * 2048 + scol;
  char* Asd = (char*)As + tid * 16;
  char* Bsd = (char*)Bs + tid * 16;

  for (int kt = 0; kt < 32; ++kt) {
    const int kb = kt * 64;
    gld_lds16(Ag + kb, Asd);
    gld_lds16(Ag + kb + 64 * 2048, Asd + 4096);
    gld_lds16(Bg + kb, Bsd);
    gld_lds16(Bg + kb + 64 * 2048, Bsd + 4096);
    __syncthreads();
    short8 af[4], bf[4];
#pragma unroll
    for (int mi = 0; mi < 4; ++mi)
      af[mi] = *(const short8*)(As + (wr * 64 + mi * 16 + lr) * 32 + lg * 8);
#pragma unroll
    for (int ni = 0; ni < 4; ++ni)
      bf[ni] = *(const short8*)(Bs + (wc * 64 + ni * 16 + lr) * 32 + lg * 8);
#pragma unroll
    for (int mi = 0; mi < 4; ++mi)
#pragma unroll
      for (int ni = 0; ni < 4; ++ni)
        acc[mi][ni] = mfma16(af[mi], bf[ni], acc[mi][ni]);
    __syncthreads();
  }

  const int f0 = f_base + wr * 64;
  const int m0 = m_base + wc * 64;
#pragma unroll
  for (int mi = 0; mi < 4; ++mi) {
    int f = f0 + mi * 16 + lg * 4;
    f32x4 bv = *(const f32x4*)(bias + f);
#pragma unroll
    for (int ni = 0; ni < 4; ++ni) {
      int m = m0 + ni * 16 + lr;
      f32x4 o = acc[mi][ni] + bv;
      *(f32x4*)(Out + (u64)m * 1024 + f) = o;
    }
  }
}

// ---------------------------------------------------------------------------
extern "C" void kernel_launch(void* const* d_in, const int* in_sizes, int n_in,
                              void* d_out, int out_size, void* d_ws,
                              size_t ws_size, hipStream_t stream) {
  const float* x = (const float*)d_in[0];       // [8,1024,1024]
  const float* w_qkv = (const float*)d_in[1];   // [3072,1024]
  const float* w_proj = (const float*)d_in[2];  // [1024,1024]
  const float* b_proj = (const float*)d_in[3];  // [1024]
  float* out = (float*)d_out;
  char* ws = (char*)d_ws;

  u16* xb = (u16*)(ws);                  // 16 MB  [8192,1024] bf16
  u16* wqb = (u16*)(ws + 16777216);      // 6 MB   [3072,1024] bf16
  u16* wpb = (u16*)(ws + 23068672);      // 2 MB   [1024,1024] bf16
  u16* qb = (u16*)(ws + 25165824);       // 16 MB  [B,H,N,D] bf16
  u16* kb = (u16*)(ws + 41943040);       // 16 MB  [B,H,N,D] bf16
  u16* vt = (u16*)(ws + 58720256);       // 16 MB  [B,H,D,N] bf16
  u16* ao = (u16*)(ws + 75497472);       // 16 MB  [8192,1024] bf16

  hipLaunchKernelGGL(cvt_bf16, dim3(2048), dim3(256), 0, stream, x, xb,
                     8192 * 1024 / 4);
  hipLaunchKernelGGL(cvt_bf16, dim3(1024), dim3(256), 0, stream, w_qkv, wqb,
                     3072 * 1024 / 4);
  hipLaunchKernelGGL(cvt_bf16, dim3(512), dim3(256), 0, stream, w_proj, wpb,
                     1024 * 1024 / 4);
  hipLaunchKernelGGL(gemm_qkv, dim3(64, 24), dim3(256), 0, stream, wqb, xb, qb,
                     kb, vt);
  hipLaunchKernelGGL(attn_fwd, dim3(2048), dim3(256), 0, stream, qb, kb, vt,
                     ao);
  hipLaunchKernelGGL(gemm_proj, dim3(64, 8), dim3(256), 0, stream, wpb, ao,
                     b_proj, out);
}

// Round 2
// 185.495 us; speedup vs baseline: 1.0076x; 1.0076x over previous
//
#include <hip/hip_runtime.h>

typedef unsigned short u16;
typedef unsigned int u32;
typedef unsigned long long u64;

typedef __attribute__((ext_vector_type(8))) short short8;
typedef __attribute__((ext_vector_type(4))) float f32x4;

#define DEVI static __device__ __forceinline__

DEVI u16 f2bf(float f) {
  u32 u = __float_as_uint(f);
  return (u16)((u + 0x7fffu + ((u >> 16) & 1u)) >> 16);
}

DEVI u64 pack4f(float a, float b, float c, float d) {
  return (u64)f2bf(a) | ((u64)f2bf(b) << 16) | ((u64)f2bf(c) << 32) |
         ((u64)f2bf(d) << 48);
}

DEVI u32 cvtpk_bf16(float lo, float hi) {
  u32 r;
  asm("v_cvt_pk_bf16_f32 %0, %1, %2" : "=v"(r) : "v"(lo), "v"(hi));
  return r;
}

DEVI void gld_lds16(const void* g, void* l) {
  __builtin_amdgcn_global_load_lds(
      (const __attribute__((address_space(1))) void*)g,
      (__attribute__((address_space(3))) void*)l, 16, 0, 0);
}

DEVI f32x4 mfma16(short8 a, short8 b, f32x4 c) {
  return __builtin_amdgcn_mfma_f32_16x16x32_bf16(a, b, c, 0, 0, 0);
}

DEVI f32x4 zero4() {
  f32x4 z = {0.f, 0.f, 0.f, 0.f};
  return z;
}

// ---------------------------------------------------------------- fp32->bf16
__global__ __launch_bounds__(256) void cvt_bf16(const float* __restrict__ s,
                                                u16* __restrict__ d, int n4) {
  int i = blockIdx.x * 256 + threadIdx.x;
  int stride = gridDim.x * 256;
  for (; i < n4; i += stride) {
    f32x4 v = ((const f32x4*)s)[i];
    ((u64*)d)[i] = pack4f(v.x, v.y, v.z, v.w);
  }
}

// ------------------------------------------------- GEMM1: qkv = W_qkv @ x^T
// C'[f, m] = sum_c W[f,c] * X[m,c].  A=W [3072,1024], B=X [8192,1024].
// Epilogue: f<1024 -> Q scaled by attn_scale*log2(e), [B,H,N,D] bf16;
//           1024<=f<2048 -> K [B,H,N,D]; f>=2048 -> V^T [B,H,D,N].
__global__ __launch_bounds__(256, 2) void gemm_qkv(
    const u16* __restrict__ W, const u16* __restrict__ X, u16* __restrict__ Q,
    u16* __restrict__ K, u16* __restrict__ V) {
  __shared__ alignas(16) char smem[36864];
  u16* As = (u16*)smem;
  u16* Bs = (u16*)(smem + 8192);

  const int tid = threadIdx.x;
  const int wid = tid >> 6, lane = tid & 63;
  const int lr = lane & 15, lg = lane >> 4;
  const int wr = wid >> 1, wc = wid & 1;
  const int f_base = blockIdx.y * 128;
  const int m_base = blockIdx.x * 128;

  f32x4 acc[4][4];
#pragma unroll
  for (int i = 0; i < 4; ++i)
#pragma unroll
    for (int j = 0; j < 4; ++j) acc[i][j] = zero4();

  const int srow = tid >> 2;
  const int scol = (tid & 3) << 4;  // bytes within 64B row-chunk
  const char* Ag = (const char*)(W + (u64)f_base * 1024) + (u64)srow * 2048 + scol;
  const char* Bg = (const char*)(X + (u64)m_base * 1024) + (u64)srow * 2048 + scol;
  char* Asd = (char*)As + tid * 16;
  char* Bsd = (char*)Bs + tid * 16;

  for (int kt = 0; kt < 32; ++kt) {
    const int kb = kt * 64;  // bytes into K
    gld_lds16(Ag + kb, Asd);
    gld_lds16(Ag + kb + 64 * 2048, Asd + 4096);
    gld_lds16(Bg + kb, Bsd);
    gld_lds16(Bg + kb + 64 * 2048, Bsd + 4096);
    __syncthreads();
    short8 af[4], bf[4];
#pragma unroll
    for (int mi = 0; mi < 4; ++mi)
      af[mi] = *(const short8*)(As + (wr * 64 + mi * 16 + lr) * 32 + lg * 8);
#pragma unroll
    for (int ni = 0; ni < 4; ++ni)
      bf[ni] = *(const short8*)(Bs + (wc * 64 + ni * 16 + lr) * 32 + lg * 8);
#pragma unroll
    for (int mi = 0; mi < 4; ++mi)
#pragma unroll
      for (int ni = 0; ni < 4; ++ni)
        acc[mi][ni] = mfma16(af[mi], bf[ni], acc[mi][ni]);
    __syncthreads();
  }

  const int f0 = f_base + wr * 64;
  const int m0 = m_base + wc * 64;
  const int b = m0 >> 10, n0 = m0 & 1023;
  const int which = f0 >> 10;        // 0=Q 1=K 2=V, uniform per wave
  const int h = (f0 & 1023) >> 6;
  const int bh = b * 16 + h;

  if (which < 2) {
    // fold softmax scale * log2(e) into Q so attention uses exp2(s - m) raw
    const float qs = (which == 0) ? (0.125f * 1.44269504088896f) : 1.f;
    u16* Ob = (u16*)smem + wid * (64 * 72);
#pragma unroll
    for (int mi = 0; mi < 4; ++mi)
#pragma unroll
      for (int ni = 0; ni < 4; ++ni) {
        int ml = ni * 16 + lr;
        int fl = mi * 16 + lg * 4;
        f32x4 a = acc[mi][ni] * qs;
        *(u64*)(Ob + ml * 72 + fl) = pack4f(a.x, a.y, a.z, a.w);
      }
    __syncthreads();
    u16* dst = (which ? K : Q) + ((u64)bh * 1024 + n0) * 64;
#pragma unroll
    for (int it = 0; it < 8; ++it) {
      int ml = it * 8 + (lane >> 3);
      int c = lane & 7;
      *(short8*)(dst + ml * 64 + c * 8) = *(const short8*)(Ob + ml * 72 + c * 8);
    }
  } else {
    u16* dst = V + (u64)bh * 64 * 1024;
#pragma unroll
    for (int mi = 0; mi < 4; ++mi) {
      int d0 = mi * 16 + lg * 4;
#pragma unroll
      for (int ni = 0; ni < 4; ++ni) {
        int n = n0 + ni * 16 + lr;
#pragma unroll
        for (int r = 0; r < 4; ++r)
          dst[(u64)(d0 + r) * 1024 + n] = f2bf(acc[mi][ni][r]);
      }
    }
  }
}

// ------------------------------------------------------------ flash attention
// Per block: one (b,h), 64 q rows (4 waves x 16).  KV tile = 64, double-
// buffered with counted vmcnt + raw barriers.  S^T = K*Q^T (swapped) so each
// lane owns one q's scores; online softmax with defer-max; P packed via
// v_cvt_pk_bf16_f32 into per-wave LDS (no barrier); O^T = V^T * P^T.
__global__ __launch_bounds__(256, 2) void attn_fwd(const u16* __restrict__ Q,
                                                   const u16* __restrict__ K,
                                                   const u16* __restrict__ V,
                                                   u16* __restrict__ AO) {
  __shared__ alignas(16) u16 Ks[2][64 * 64];
  __shared__ alignas(16) u16 Vs[2][64 * 64];
  __shared__ alignas(16) u16 Pb[4 * 16 * 72];

  const int tid = threadIdx.x;
  const int wid = tid >> 6, lane = tid & 63;
  const int lr = lane & 15, lg = lane >> 4;
  const int bh = blockIdx.x >> 4, qblk = blockIdx.x & 15;

  const u64 kvbase = (u64)bh * (1024 * 64);
  const int q0 = qblk * 64 + wid * 16;

  const u16* qp = Q + kvbase + (u64)(q0 + lr) * 64 + lg * 8;
  const short8 qf0 = *(const short8*)qp;
  const short8 qf1 = *(const short8*)(qp + 32);

  float m_run = -INFINITY, l_run = 0.f;
  f32x4 oacc[4];
#pragma unroll
  for (int i = 0; i < 4; ++i) oacc[i] = zero4();

  u16* Pw = Pb + wid * (16 * 72);
  const int t2 = tid + 256;
  const int r1 = tid >> 3, c1 = tid & 7;
  const int r2 = t2 >> 3, c2 = t2 & 7;
  const int ksw1 = r1 * 128 + ((c1 ^ (r1 & 7)) << 4);
  const int ksw2 = r2 * 128 + ((c2 ^ (r2 & 7)) << 4);
  const int vsw1 = r1 * 2048 + ((c1 ^ (r1 & 7)) << 4);
  const int vsw2 = r2 * 2048 + ((c2 ^ (r2 & 7)) << 4);

  // loop-invariant LDS byte offsets for fragment reads
  int koff0[4], koff1[4], voff0[4], voff1[4];
#pragma unroll
  for (int i = 0; i < 4; ++i) {
    int row = i * 16 + lr;
    int sw = row & 7;
    koff0[i] = row * 128 + ((lg ^ sw) << 4);
    koff1[i] = row * 128 + (((lg + 4) ^ sw) << 4);
    voff0[i] = koff0[i];
    voff1[i] = koff1[i];
  }

  const char* kgb = (const char*)(K + kvbase);
  const char* vgb = (const char*)(V + kvbase);

#define STAGE(buf, kt)                                                      \
  do {                                                                      \
    const char* kg = kgb + (kt) * 8192;                                     \
    gld_lds16(kg + ksw1, (char*)Ks[buf] + tid * 16);                        \
    gld_lds16(kg + ksw2, (char*)Ks[buf] + t2 * 16);                         \
    const char* vg = vgb + (kt) * 128;                                      \
    gld_lds16(vg + vsw1, (char*)Vs[buf] + tid * 16);                        \
    gld_lds16(vg + vsw2, (char*)Vs[buf] + t2 * 16);                         \
  } while (0)

  STAGE(0, 0);

  for (int kt = 0; kt < 16; ++kt) {
    const int cur = kt & 1;
    if (kt + 1 < 16) {
      STAGE(cur ^ 1, kt + 1);
      asm volatile("s_waitcnt vmcnt(4)" ::: "memory");
    } else {
      asm volatile("s_waitcnt vmcnt(0)" ::: "memory");
    }
    __builtin_amdgcn_s_barrier();
    asm volatile("" ::: "memory");

    const u16* Kc = Ks[cur];
    const u16* Vc = Vs[cur];

    // S^T = K * Q^T  (Q pre-scaled by attn_scale*log2e in gemm_qkv)
    f32x4 sacc[4];
#pragma unroll
    for (int m4 = 0; m4 < 4; ++m4) sacc[m4] = zero4();
#pragma unroll
    for (int m4 = 0; m4 < 4; ++m4) {
      short8 kf0 = *(const short8*)((const char*)Kc + koff0[m4]);
      short8 kf1 = *(const short8*)((const char*)Kc + koff1[m4]);
      sacc[m4] = mfma16(kf0, qf0, sacc[m4]);
      sacc[m4] = mfma16(kf1, qf1, sacc[m4]);
    }

    // online softmax (each q owned by 4 lanes: lr, +16, +32, +48)
    float pmax = -INFINITY;
#pragma unroll
    for (int m4 = 0; m4 < 4; ++m4)
#pragma unroll
      for (int r = 0; r < 4; ++r) pmax = fmaxf(pmax, sacc[m4][r]);
    pmax = fmaxf(pmax, __shfl_xor(pmax, 16));
    pmax = fmaxf(pmax, __shfl_xor(pmax, 32));

    // defer-max: only rescale when the running max grew by > 8 (log2 units)
    if (__any(pmax - m_run > 8.f)) {
      float m_new = fmaxf(m_run, pmax);
      float alpha = exp2f(m_run - m_new);
      l_run *= alpha;
#pragma unroll
      for (int dt = 0; dt < 4; ++dt) oacc[dt] *= alpha;
      m_run = m_new;
    }

    float psum = 0.f;
    float p[16];
#pragma unroll
    for (int m4 = 0; m4 < 4; ++m4)
#pragma unroll
      for (int r = 0; r < 4; ++r) {
        float e = exp2f(sacc[m4][r] - m_run);
        p[m4 * 4 + r] = e;
        psum += e;
      }
    psum += __shfl_xor(psum, 16);
    psum += __shfl_xor(psum, 32);
    l_run += psum;

    // pack P (bf16) into per-wave LDS: Pw[q][key]  (wave-local, no barrier)
#pragma unroll
    for (int m4 = 0; m4 < 4; ++m4) {
      u64 w = (u64)cvtpk_bf16(p[m4 * 4], p[m4 * 4 + 1]) |
              ((u64)cvtpk_bf16(p[m4 * 4 + 2], p[m4 * 4 + 3]) << 32);
      *(u64*)(Pw + lr * 72 + m4 * 16 + lg * 4) = w;
    }

    short8 pf0 = *(const short8*)(Pw + lr * 72 + lg * 8);
    short8 pf1 = *(const short8*)(Pw + lr * 72 + 32 + lg * 8);
#pragma unroll
    for (int dt = 0; dt < 4; ++dt) {
      short8 vf0 = *(const short8*)((const char*)Vc + voff0[dt]);
      short8 vf1 = *(const short8*)((const char*)Vc + voff1[dt]);
      oacc[dt] = mfma16(vf0, pf0, oacc[dt]);
      oacc[dt] = mfma16(vf1, pf1, oacc[dt]);
    }

    asm volatile("" ::: "memory");
    __builtin_amdgcn_s_barrier();
    asm volatile("" ::: "memory");
  }
#undef STAGE

  // epilogue: normalize, transpose via per-wave LDS, coalesced store
  float inv_l = 1.f / l_run;
#pragma unroll
  for (int dt = 0; dt < 4; ++dt) {
    f32x4 o = oacc[dt] * inv_l;
    u64 w = (u64)cvtpk_bf16(o.x, o.y) | ((u64)cvtpk_bf16(o.z, o.w) << 32);
    *(u64*)(Pw + lr * 72 + dt * 16 + lg * 4) = w;
  }
  const int b = bh >> 4, h = bh & 15;
  u16* dst = AO + ((u64)(b * 1024 + q0) * 1024) + h * 64;
#pragma unroll
  for (int it = 0; it < 2; ++it) {
    int ql = it * 8 + (lane >> 3);
    int c = lane & 7;
    *(short8*)(dst + (u64)ql * 1024 + c * 8) = *(const short8*)(Pw + ql * 72 + c * 8);
  }
}

// ----------------------------------------------- GEMM2: out = AO @ Wp^T + b
// C'[f, m] orientation; fp32 output with fused bias, f32x4 stores.
__global__ __launch_bounds__(256, 2) void gemm_proj(const u16* __restrict__ W,
                                                    const u16* __restrict__ X,
                                                    const float* __restrict__ bias,
                                                    float* __restrict__ Out) {
  __shared__ alignas(16) char smem[16384];
  u16* As = (u16*)smem;
  u16* Bs = (u16*)(smem + 8192);

  const int tid = threadIdx.x;
  const int wid = tid >> 6, lane = tid & 63;
  const int lr = lane & 15, lg = lane >> 4;
  const int wr = wid >> 1, wc = wid & 1;
  const int f_base = blockIdx.y * 128;
  const int m_base = blockIdx.x * 128;

  f32x4 acc[4][4];
#pragma unroll
  for (int i = 0; i < 4; ++i)
#pragma unroll
    for (int j = 0; j < 4; ++j) acc[i][j] = zero4();

  const int srow = tid >> 2;
  const int scol = (tid & 3) << 4;
  const char* Ag = (const char*)(W + (u64)f_base * 1024) + (u64)srow * 2048 + scol;
  const char* Bg = (const char*)(X + (u64)m_base * 1024) + (u64)srow * 2048 + scol;
  char* Asd = (char*)As + tid * 16;
  char* Bsd = (char*)Bs + tid * 16;

  for (int kt = 0; kt < 32; ++kt) {
    const int kb = kt * 64;
    gld_lds16(Ag + kb, Asd);
    gld_lds16(Ag + kb + 64 * 2048, Asd + 4096);
    gld_lds16(Bg + kb, Bsd);
    gld_lds16(Bg + kb + 64 * 2048, Bsd + 4096);
    __syncthreads();
    short8 af[4], bf[4];
#pragma unroll
    for (int mi = 0; mi < 4; ++mi)
      af[mi] = *(const short8*)(As + (wr * 64 + mi * 16 + lr) * 32 + lg * 8);
#pragma unroll
    for (int ni = 0; ni < 4; ++ni)
      bf[ni] = *(const short8*)(Bs + (wc * 64 + ni * 16 + lr) * 32 + lg * 8);
#pragma unroll
    for (int mi = 0; mi < 4; ++mi)
#pragma unroll
      for (int ni = 0; ni < 4; ++ni)
        acc[mi][ni] = mfma16(af[mi], bf[ni], acc[mi][ni]);
    __syncthreads();
  }

  const int f0 = f_base + wr * 64;
  const int m0 = m_base + wc * 64;
#pragma unroll
  for (int mi = 0; mi < 4; ++mi) {
    int f = f0 + mi * 16 + lg * 4;
    f32x4 bv = *(const f32x4*)(bias + f);
#pragma unroll
    for (int ni = 0; ni < 4; ++ni) {
      int m = m0 + ni * 16 + lr;
      f32x4 o = acc[mi][ni] + bv;
      *(f32x4*)(Out + (u64)m * 1024 + f) = o;
    }
  }
}

// ---------------------------------------------------------------------------
extern "C" void kernel_launch(void* const* d_in, const int* in_sizes, int n_in,
                              void* d_out, int out_size, void* d_ws,
                              size_t ws_size, hipStream_t stream) {
  const float* x = (const float*)d_in[0];       // [8,1024,1024]
  const float* w_qkv = (const float*)d_in[1];   // [3072,1024]
  const float* w_proj = (const float*)d_in[2];  // [1024,1024]
  const float* b_proj = (const float*)d_in[3];  // [1024]
  float* out = (float*)d_out;
  char* ws = (char*)d_ws;

  u16* xb = (u16*)(ws);                  // 16 MB  [8192,1024] bf16
  u16* wqb = (u16*)(ws + 16777216);      // 6 MB   [3072,1024] bf16
  u16* wpb = (u16*)(ws + 23068672);      // 2 MB   [1024,1024] bf16
  u16* qb = (u16*)(ws + 25165824);       // 16 MB  [B,H,N,D] bf16 (pre-scaled)
  u16* kb = (u16*)(ws + 41943040);       // 16 MB  [B,H,N,D] bf16
  u16* vt = (u16*)(ws + 58720256);       // 16 MB  [B,H,D,N] bf16
  u16* ao = (u16*)(ws + 75497472);       // 16 MB  [8192,1024] bf16

  hipLaunchKernelGGL(cvt_bf16, dim3(2048), dim3(256), 0, stream, x, xb,
                     8192 * 1024 / 4);
  hipLaunchKernelGGL(cvt_bf16, dim3(1024), dim3(256), 0, stream, w_qkv, wqb,
                     3072 * 1024 / 4);
  hipLaunchKernelGGL(cvt_bf16, dim3(512), dim3(256), 0, stream, w_proj, wpb,
                     1024 * 1024 / 4);
  hipLaunchKernelGGL(gemm_qkv, dim3(64, 24), dim3(256), 0, stream, wqb, xb, qb,
                     kb, vt);
  hipLaunchKernelGGL(attn_fwd, dim3(2048), dim3(256), 0, stream, qb, kb, vt,
                     ao);
  hipLaunchKernelGGL(gemm_proj, dim3(64, 8), dim3(256), 0, stream, wpb, ao,
                     b_proj, out);
}

// Round 3
// 172.872 us; speedup vs baseline: 1.0811x; 1.0730x over previous
//
#include <hip/hip_runtime.h>

typedef unsigned short u16;
typedef unsigned int u32;
typedef unsigned long long u64;

typedef __attribute__((ext_vector_type(8))) short short8;
typedef __attribute__((ext_vector_type(4))) float f32x4;
typedef __attribute__((ext_vector_type(16))) float f32x16;
typedef __attribute__((ext_vector_type(4))) u32 u32x4;

#define DEVI static __device__ __forceinline__

DEVI u16 f2bf(float f) {
  u32 u = __float_as_uint(f);
  return (u16)((u + 0x7fffu + ((u >> 16) & 1u)) >> 16);
}

DEVI u64 pack4f(float a, float b, float c, float d) {
  return (u64)f2bf(a) | ((u64)f2bf(b) << 16) | ((u64)f2bf(c) << 32) |
         ((u64)f2bf(d) << 48);
}

DEVI u32 cvtpk_bf16(float lo, float hi) {
  u32 r;
  asm("v_cvt_pk_bf16_f32 %0, %1, %2" : "=v"(r) : "v"(lo), "v"(hi));
  return r;
}

DEVI void gld_lds16(const void* g, void* l) {
  __builtin_amdgcn_global_load_lds(
      (const __attribute__((address_space(1))) void*)g,
      (__attribute__((address_space(3))) void*)l, 16, 0, 0);
}

DEVI f32x4 mfma16(short8 a, short8 b, f32x4 c) {
  return __builtin_amdgcn_mfma_f32_16x16x32_bf16(a, b, c, 0, 0, 0);
}

DEVI f32x16 mfma32(short8 a, short8 b, f32x16 c) {
  return __builtin_amdgcn_mfma_f32_32x32x16_bf16(a, b, c, 0, 0, 0);
}

DEVI f32x4 zero4() {
  f32x4 z = {0.f, 0.f, 0.f, 0.f};
  return z;
}

// ---------------------------------------------------------------- fp32->bf16
__global__ __launch_bounds__(256) void cvt_bf16(const float* __restrict__ s,
                                                u16* __restrict__ d, int n4) {
  int i = blockIdx.x * 256 + threadIdx.x;
  int stride = gridDim.x * 256;
  for (; i < n4; i += stride) {
    f32x4 v = ((const f32x4*)s)[i];
    ((u64*)d)[i] = pack4f(v.x, v.y, v.z, v.w);
  }
}

// ------------------------------------------------- GEMM1: qkv = W_qkv @ x^T
__global__ __launch_bounds__(256, 2) void gemm_qkv(
    const u16* __restrict__ W, const u16* __restrict__ X, u16* __restrict__ Q,
    u16* __restrict__ K, u16* __restrict__ V) {
  __shared__ alignas(16) char smem[36864];
  u16* As = (u16*)smem;
  u16* Bs = (u16*)(smem + 8192);

  const int tid = threadIdx.x;
  const int wid = tid >> 6, lane = tid & 63;
  const int lr = lane & 15, lg = lane >> 4;
  const int wr = wid >> 1, wc = wid & 1;
  const int f_base = blockIdx.y * 128;
  const int m_base = blockIdx.x * 128;

  f32x4 acc[4][4];
#pragma unroll
  for (int i = 0; i < 4; ++i)
#pragma unroll
    for (int j = 0; j < 4; ++j) acc[i][j] = zero4();

  const int srow = tid >> 2;
  const int scol = (tid & 3) << 4;
  const char* Ag = (const char*)(W + (u64)f_base * 1024) + (u64)srow * 2048 + scol;
  const char* Bg = (const char*)(X + (u64)m_base * 1024) + (u64)srow * 2048 + scol;
  char* Asd = (char*)As + tid * 16;
  char* Bsd = (char*)Bs + tid * 16;

  for (int kt = 0; kt < 32; ++kt) {
    const int kb = kt * 64;
    gld_lds16(Ag + kb, Asd);
    gld_lds16(Ag + kb + 64 * 2048, Asd + 4096);
    gld_lds16(Bg + kb, Bsd);
    gld_lds16(Bg + kb + 64 * 2048, Bsd + 4096);
    __syncthreads();
    short8 af[4], bf[4];
#pragma unroll
    for (int mi = 0; mi < 4; ++mi)
      af[mi] = *(const short8*)(As + (wr * 64 + mi * 16 + lr) * 32 + lg * 8);
#pragma unroll
    for (int ni = 0; ni < 4; ++ni)
      bf[ni] = *(const short8*)(Bs + (wc * 64 + ni * 16 + lr) * 32 + lg * 8);
#pragma unroll
    for (int mi = 0; mi < 4; ++mi)
#pragma unroll
      for (int ni = 0; ni < 4; ++ni)
        acc[mi][ni] = mfma16(af[mi], bf[ni], acc[mi][ni]);
    __syncthreads();
  }

  const int f0 = f_base + wr * 64;
  const int m0 = m_base + wc * 64;
  const int b = m0 >> 10, n0 = m0 & 1023;
  const int which = f0 >> 10;
  const int h = (f0 & 1023) >> 6;
  const int bh = b * 16 + h;

  if (which < 2) {
    // fold softmax scale * log2(e) into Q
    const float qs = (which == 0) ? (0.125f * 1.44269504088896f) : 1.f;
    u16* Ob = (u16*)smem + wid * (64 * 72);
#pragma unroll
    for (int mi = 0; mi < 4; ++mi)
#pragma unroll
      for (int ni = 0; ni < 4; ++ni) {
        int ml = ni * 16 + lr;
        int fl = mi * 16 + lg * 4;
        f32x4 a = acc[mi][ni] * qs;
        *(u64*)(Ob + ml * 72 + fl) = pack4f(a.x, a.y, a.z, a.w);
      }
    __syncthreads();
    u16* dst = (which ? K : Q) + ((u64)bh * 1024 + n0) * 64;
#pragma unroll
    for (int it = 0; it < 8; ++it) {
      int ml = it * 8 + (lane >> 3);
      int c = lane & 7;
      *(short8*)(dst + ml * 64 + c * 8) = *(const short8*)(Ob + ml * 72 + c * 8);
    }
  } else {
    u16* dst = V + (u64)bh * 64 * 1024;
#pragma unroll
    for (int mi = 0; mi < 4; ++mi) {
      int d0 = mi * 16 + lg * 4;
#pragma unroll
      for (int ni = 0; ni < 4; ++ni) {
        int n = n0 + ni * 16 + lr;
#pragma unroll
        for (int r = 0; r < 4; ++r)
          dst[(u64)(d0 + r) * 1024 + n] = f2bf(acc[mi][ni][r]);
      }
    }
  }
}

// ------------------------------------------------------------ flash attention
// 32x32x16 MFMA structure: 4 waves x 32 q rows = 128 q / block; 1024 blocks.
// Swapped S^T = K*Q^T so each lane owns one full q row (softmax fully in
// register; no P LDS round-trip).  K/V tiles staged in chunk-column LDS
// layout ([chunk16B][row]) -> fragment reads are 512B-contiguous, 0 bank
// conflicts, and global_load_lds needs no swizzle.  KVBLK=64, double-buffered
// with counted vmcnt.  XCD-aware block map keeps each (b,h) on one XCD.
__global__ __launch_bounds__(256, 4) void attn_fwd(const u16* __restrict__ Q,
                                                   const u16* __restrict__ K,
                                                   const u16* __restrict__ V,
                                                   u16* __restrict__ AO) {
  __shared__ alignas(16) u16 Ks[2][4096];  // 8KB per buf, chunk-col layout
  __shared__ alignas(16) u16 Vs[2][4096];

  const int tid = threadIdx.x;
  const int wid = tid >> 6, lane = tid & 63;
  const int l31 = lane & 31, hi = lane >> 5;

  // XCD-aware map: 8 q-blocks of one bh stay on one XCD
  const int i = blockIdx.x;
  const int qblk = (i >> 3) & 7;
  const int bh = (i & 7) * 16 + (i >> 6);

  const u64 kvbase = (u64)bh * (1024 * 64);
  const int q0w = qblk * 128 + wid * 32;

  // Q fragments (B operand): q=l31's row, d = 16*ss + 8*hi + {0..7}
  short8 qf[4];
  {
    const char* qrow = (const char*)(Q + kvbase + (u64)(q0w + l31) * 64);
#pragma unroll
    for (int ss = 0; ss < 4; ++ss)
      qf[ss] = *(const short8*)(qrow + 32 * ss + 16 * hi);
  }

  float m_run = -INFINITY, l_run = 0.f;
  f32x16 o0 = {0}, o1 = {0};

  // staging: chunk-col layout, slot = c*64 + r, dest byte = 16*slot (linear)
  const int sr = tid & 63, scc = tid >> 6;  // row 0..63, chunk 0..3
  const char* kgb = (const char*)(K + kvbase);
  const char* vgb = (const char*)(V + kvbase);

#define STAGE(buf, kt)                                                       \
  do {                                                                       \
    const char* kg = kgb + (u64)(kt) * 8192;                                 \
    const char* vg = vgb + (kt) * 128;                                       \
    gld_lds16(kg + sr * 128 + scc * 16, (char*)Ks[buf] + tid * 16);          \
    gld_lds16(kg + sr * 128 + (scc + 4) * 16,                                \
              (char*)Ks[buf] + (tid + 256) * 16);                            \
    gld_lds16(vg + sr * 2048 + scc * 16, (char*)Vs[buf] + tid * 16);         \
    gld_lds16(vg + sr * 2048 + (scc + 4) * 16,                               \
              (char*)Vs[buf] + (tid + 256) * 16);                            \
  } while (0)

  STAGE(0, 0);

  for (int kt = 0; kt < 16; ++kt) {
    const int cur = kt & 1;
    if (kt + 1 < 16) {
      STAGE(cur ^ 1, kt + 1);
      asm volatile("s_waitcnt vmcnt(4)" ::: "memory");
    } else {
      asm volatile("s_waitcnt vmcnt(0)" ::: "memory");
    }
    __builtin_amdgcn_s_barrier();
    asm volatile("" ::: "memory");

    const char* Kc = (const char*)Ks[cur];
    const char* Vc = (const char*)Vs[cur];

    // ---- S^T = K * Q^T : A-frag = K rows (k=32t+l31), k-dim = d
    f32x16 s0 = {0}, s1 = {0};
#pragma unroll
    for (int ss = 0; ss < 4; ++ss) {
      const int ch = (2 * ss + hi) << 10;
      short8 kf0 = *(const short8*)(Kc + ch + (l31 << 4));
      short8 kf1 = *(const short8*)(Kc + ch + ((32 + l31) << 4));
      s0 = mfma32(kf0, qf[ss], s0);
      s1 = mfma32(kf1, qf[ss], s1);
    }

    // ---- softmax, fully lane-local (lane owns q row l31, k-half hi)
    float t[16];
#pragma unroll
    for (int j = 0; j < 16; ++j) t[j] = fmaxf(s0[j], s1[j]);
#pragma unroll
    for (int j = 0; j < 8; ++j) t[j] = fmaxf(t[j], t[j + 8]);
#pragma unroll
    for (int j = 0; j < 4; ++j) t[j] = fmaxf(t[j], t[j + 4]);
    float pm = fmaxf(fmaxf(t[0], t[1]), fmaxf(t[2], t[3]));
    pm = fmaxf(pm, __shfl_xor(pm, 32));

    if (__any(pm - m_run > 8.f)) {  // defer-max (T13)
      float m_new = fmaxf(m_run, pm);
      float alpha = exp2f(m_run - m_new);
      l_run *= alpha;
#pragma unroll
      for (int j = 0; j < 16; ++j) {
        o0[j] *= alpha;
        o1[j] *= alpha;
      }
      m_run = m_new;
    }

#pragma unroll
    for (int j = 0; j < 16; ++j) {
      s0[j] = exp2f(s0[j] - m_run);
      s1[j] = exp2f(s1[j] - m_run);
    }
    float u[16];
#pragma unroll
    for (int j = 0; j < 16; ++j) u[j] = s0[j] + s1[j];
#pragma unroll
    for (int j = 0; j < 8; ++j) u[j] += u[j + 8];
#pragma unroll
    for (int j = 0; j < 4; ++j) u[j] += u[j + 4];
    float psum = (u[0] + u[1]) + (u[2] + u[3]);
    psum += __shfl_xor(psum, 32);
    l_run += psum;

    // ---- PV: P fragments assembled in-register (cvt_pk + half-exchange)
#pragma unroll
    for (int s = 0; s < 4; ++s) {
      // p regs for step s: s<2 -> s0[8*s .. 8*s+7], else s1[8*(s-2) ..]
      float p0, p1, p2, p3, p4, p5, p6, p7;
      if (s == 0) {
        p0 = s0[0]; p1 = s0[1]; p2 = s0[2]; p3 = s0[3];
        p4 = s0[4]; p5 = s0[5]; p6 = s0[6]; p7 = s0[7];
      } else if (s == 1) {
        p0 = s0[8]; p1 = s0[9]; p2 = s0[10]; p3 = s0[11];
        p4 = s0[12]; p5 = s0[13]; p6 = s0[14]; p7 = s0[15];
      } else if (s == 2) {
        p0 = s1[0]; p1 = s1[1]; p2 = s1[2]; p3 = s1[3];
        p4 = s1[4]; p5 = s1[5]; p6 = s1[6]; p7 = s1[7];
      } else {
        p0 = s1[8]; p1 = s1[9]; p2 = s1[10]; p3 = s1[11];
        p4 = s1[12]; p5 = s1[13]; p6 = s1[14]; p7 = s1[15];
      }
      u32 w0 = cvtpk_bf16(p0, p1);  // k = 16s+4hi+{0,1}
      u32 w1 = cvtpk_bf16(p2, p3);  // k = 16s+4hi+{2,3}
      u32 w2 = cvtpk_bf16(p4, p5);  // k = 16s+8+4hi+{0,1}
      u32 w3 = cvtpk_bf16(p6, p7);  // k = 16s+8+4hi+{2,3}
      u32 t0 = __shfl_xor(w0, 32);
      u32 t1 = __shfl_xor(w1, 32);
      u32 t2 = __shfl_xor(w2, 32);
      u32 t3 = __shfl_xor(w3, 32);
      u32x4 pw;
      pw.x = hi ? t2 : w0;  // k = 16s + 8hi + {0,1}
      pw.y = hi ? t3 : w1;  //            + {2,3}
      pw.z = hi ? w2 : t0;  //            + {4,5}
      pw.w = hi ? w3 : t1;  //            + {6,7}
      short8 pf = __builtin_bit_cast(short8, pw);

      const int ch = (2 * s + hi) << 10;
      short8 vf0 = *(const short8*)(Vc + ch + (l31 << 4));
      short8 vf1 = *(const short8*)(Vc + ch + ((32 + l31) << 4));
      o0 = mfma32(vf0, pf, o0);
      o1 = mfma32(vf1, pf, o1);
    }

    asm volatile("" ::: "memory");
    __builtin_amdgcn_s_barrier();
    asm volatile("" ::: "memory");
  }
#undef STAGE

  // ---- epilogue: normalize, per-wave LDS transpose, coalesced store
  __syncthreads();  // all waves done reading K/V LDS
  float inv_l = 1.f / l_run;
  u16* Ob = (u16*)((char*)Ks + wid * 4096);  // [32 q][64 d], swizzled chunks
#pragma unroll
  for (int j4 = 0; j4 < 4; ++j4) {
    // o0 quad j4: d = 8*j4 + 4*hi + {0..3};  o1: d += 32
    u64 wa = (u64)cvtpk_bf16(o0[4 * j4] * inv_l, o0[4 * j4 + 1] * inv_l) |
             ((u64)cvtpk_bf16(o0[4 * j4 + 2] * inv_l, o0[4 * j4 + 3] * inv_l)
              << 32);
    u64 wb = (u64)cvtpk_bf16(o1[4 * j4] * inv_l, o1[4 * j4 + 1] * inv_l) |
             ((u64)cvtpk_bf16(o1[4 * j4 + 2] * inv_l, o1[4 * j4 + 3] * inv_l)
              << 32);
    *(u64*)(Ob + l31 * 64 + (((j4 ^ (l31 & 7)) << 4) + 8 * hi) / 2) = wa;
    *(u64*)(Ob + l31 * 64 + ((((4 + j4) ^ (l31 & 7)) << 4) + 8 * hi) / 2) = wb;
  }
  // wave-local: LDS writes then reads by same wave; compiler inserts lgkmcnt
  const int b = bh >> 4, h = bh & 15;
#pragma unroll
  for (int it = 0; it < 4; ++it) {
    int qr = it * 8 + (lane >> 3);
    int cd = lane & 7;
    short8 vvv = *(const short8*)(Ob + qr * 64 + (((cd ^ (qr & 7)) << 4) / 2));
    u16* dst = AO + ((u64)(b * 1024 + q0w + qr) * 1024 + h * 64 + cd * 8);
    *(short8*)dst = vvv;
  }
}

// ----------------------------------------------- GEMM2: out = AO @ Wp^T + b
__global__ __launch_bounds__(256, 2) void gemm_proj(const u16* __restrict__ W,
                                                    const u16* __restrict__ X,
                                                    const float* __restrict__ bias,
                                                    float* __restrict__ Out) {
  __shared__ alignas(16) char smem[16384];
  u16* As = (u16*)smem;
  u16* Bs = (u16*)(smem + 8192);

  const int tid = threadIdx.x;
  const int wid = tid >> 6, lane = tid & 63;
  const int lr = lane & 15, lg = lane >> 4;
  const int wr = wid >> 1, wc = wid & 1;
  const int f_base = blockIdx.y * 128;
  const int m_base = blockIdx.x * 128;

  f32x4 acc[4][4];
#pragma unroll
  for (int i = 0; i < 4; ++i)
#pragma unroll
    for (int j = 0; j < 4; ++j) acc[i][j] = zero4();

  const int srow = tid >> 2;
  const int scol = (tid & 3) << 4;
  const char* Ag = (const char*)(W + (u64)f_base * 1024) + (u64)srow * 2048 + scol;
  const char* Bg = (const char*)(X + (u64)m_base * 1024) + (u64)srow * 2048 + scol;
  char* Asd = (char*)As + tid * 16;
  char* Bsd = (char*)Bs + tid * 16;

  for (int kt = 0; kt < 32; ++kt) {
    const int kb = kt * 64;
    gld_lds16(Ag + kb, Asd);
    gld_lds16(Ag + kb + 64 * 2048, Asd + 4096);
    gld_lds16(Bg + kb, Bsd);
    gld_lds16(Bg + kb + 64 * 2048, Bsd + 4096);
    __syncthreads();
    short8 af[4], bf[4];
#pragma unroll
    for (int mi = 0; mi < 4; ++mi)
      af[mi] = *(const short8*)(As + (wr * 64 + mi * 16 + lr) * 32 + lg * 8);
#pragma unroll
    for (int ni = 0; ni < 4; ++ni)
      bf[ni] = *(const short8*)(Bs + (wc * 64 + ni * 16 + lr) * 32 + lg * 8);
#pragma unroll
    for (int mi = 0; mi < 4; ++mi)
#pragma unroll
      for (int ni = 0; ni < 4; ++ni)
        acc[mi][ni] = mfma16(af[mi], bf[ni], acc[mi][ni]);
    __syncthreads();
  }

  const int f0 = f_base + wr * 64;
  const int m0 = m_base + wc * 64;
#pragma unroll
  for (int mi = 0; mi < 4; ++mi) {
    int f = f0 + mi * 16 + lg * 4;
    f32x4 bv = *(const f32x4*)(bias + f);
#pragma unroll
    for (int ni = 0; ni < 4; ++ni) {
      int m = m0 + ni * 16 + lr;
      f32x4 o = acc[mi][ni] + bv;
      *(f32x4*)(Out + (u64)m * 1024 + f) = o;
    }
  }
}

// ---------------------------------------------------------------------------
extern "C" void kernel_launch(void* const* d_in, const int* in_sizes, int n_in,
                              void* d_out, int out_size, void* d_ws,
                              size_t ws_size, hipStream_t stream) {
  const float* x = (const float*)d_in[0];
  const float* w_qkv = (const float*)d_in[1];
  const float* w_proj = (const float*)d_in[2];
  const float* b_proj = (const float*)d_in[3];
  float* out = (float*)d_out;
  char* ws = (char*)d_ws;

  u16* xb = (u16*)(ws);                  // 16 MB  [8192,1024] bf16
  u16* wqb = (u16*)(ws + 16777216);      // 6 MB   [3072,1024] bf16
  u16* wpb = (u16*)(ws + 23068672);      // 2 MB   [1024,1024] bf16
  u16* qb = (u16*)(ws + 25165824);       // 16 MB  [B,H,N,D] bf16 (pre-scaled)
  u16* kb = (u16*)(ws + 41943040);       // 16 MB  [B,H,N,D] bf16
  u16* vt = (u16*)(ws + 58720256);       // 16 MB  [B,H,D,N] bf16
  u16* ao = (u16*)(ws + 75497472);       // 16 MB  [8192,1024] bf16

  hipLaunchKernelGGL(cvt_bf16, dim3(2048), dim3(256), 0, stream, x, xb,
                     8192 * 1024 / 4);
  hipLaunchKernelGGL(cvt_bf16, dim3(1024), dim3(256), 0, stream, w_qkv, wqb,
                     3072 * 1024 / 4);
  hipLaunchKernelGGL(cvt_bf16, dim3(512), dim3(256), 0, stream, w_proj, wpb,
                     1024 * 1024 / 4);
  hipLaunchKernelGGL(gemm_qkv, dim3(64, 24), dim3(256), 0, stream, wqb, xb, qb,
                     kb, vt);
  hipLaunchKernelGGL(attn_fwd, dim3(1024), dim3(256), 0, stream, qb, kb, vt,
                     ao);
  hipLaunchKernelGGL(gemm_proj, dim3(64, 8), dim3(256), 0, stream, wpb, ao,
                     b_proj, out);
}